// Round 1
// baseline (20873.779 us; speedup 1.0000x reference)
//
#include <hip/hip_runtime.h>
#include <hip/hip_bf16.h>
#include <math.h>

namespace {

constexpr int B = 1024, T = 256, E = 128;
constexpr int BT = B * T;

__device__ __forceinline__ float sgm(float x){ return 1.0f/(1.0f + __expf(-x)); }
__device__ __forceinline__ float cvt(float v){ return v; }
__device__ __forceinline__ float cvt(__hip_bfloat16 v){ return __bfloat162float(v); }

// ---------- prep: fold/transpose small weights ----------
__global__ void k_prep(const float* __restrict__ W1, const float* __restrict__ W2,
                       const float* __restrict__ w_ir, const float* __restrict__ w_iz, const float* __restrict__ w_ih,
                       const float* __restrict__ b_ir, const float* __restrict__ b_hr,
                       const float* __restrict__ b_iz, const float* __restrict__ b_hz,
                       const float* __restrict__ b_ih,
                       float* __restrict__ wqT, float* __restrict__ wxT, float* __restrict__ wqxT,
                       float* __restrict__ W2T, float* __restrict__ wcat, float* __restrict__ bcat)
{
  int tid = blockIdx.x*blockDim.x + threadIdx.x;
  int nth = gridDim.x*blockDim.x;
  for (int i = tid; i < 32*128; i += nth){
    int c = i >> 7, e = i & 127;
    float wa = W1[e*32 + c];
    float wb = W1[(128+e)*32 + c];
    float wc = W1[(256+e)*32 + c];
    float wd = W1[(384+e)*32 + c];
    wqT[i]  = wa + wc;     // q coefficient
    wxT[i]  = wb - wc;     // x coefficient
    wqxT[i] = wd;          // q*x coefficient
  }
  for (int i = tid; i < 16*32; i += nth){
    int d = i >> 5, c = i & 31;
    W2T[i] = W2[c*16 + d];
  }
  for (int i = tid; i < 128*384; i += nth){
    int e = i / 384, j = i - e*384;
    float v;
    if (j < 128)      v = w_ir[e*128 + j];
    else if (j < 256) v = w_iz[e*128 + j - 128];
    else              v = w_ih[e*128 + j - 256];
    wcat[i] = v;
  }
  for (int j = tid; j < 384; j += nth){
    float v;
    if (j < 128)      v = b_ir[j] + b_hr[j];
    else if (j < 256) v = b_iz[j-128] + b_hz[j-128];
    else              v = b_ih[j-256];
    bcat[j] = v;
  }
}

// ---------- attention dense 1 (pre-activation) ----------
__global__ void k_h1(const float* __restrict__ q, const float* __restrict__ x,
                     const float* __restrict__ wqT, const float* __restrict__ wxT, const float* __restrict__ wqxT,
                     const float* __restrict__ b1, float* __restrict__ h1)
{
  int c = threadIdx.x & 31;
  int p = threadIdx.x >> 5;
  int bt = blockIdx.x*8 + p;
  int b = bt >> 8;
  const float4* qp  = (const float4*)(q + (size_t)b*E);
  const float4* xp  = (const float4*)(x + (size_t)bt*E);
  const float4* wq4 = (const float4*)(wqT + c*E);
  const float4* wx4 = (const float4*)(wxT + c*E);
  const float4* wp4 = (const float4*)(wqxT + c*E);
  float acc = b1[c];
  #pragma unroll 8
  for (int e4 = 0; e4 < 32; ++e4){
    float4 qv = qp[e4], xv = xp[e4];
    float4 aw = wq4[e4], bw = wx4[e4], cw = wp4[e4];
    acc = fmaf(qv.x, aw.x, acc); acc = fmaf(xv.x, bw.x, acc); acc = fmaf(qv.x*xv.x, cw.x, acc);
    acc = fmaf(qv.y, aw.y, acc); acc = fmaf(xv.y, bw.y, acc); acc = fmaf(qv.y*xv.y, cw.y, acc);
    acc = fmaf(qv.z, aw.z, acc); acc = fmaf(xv.z, bw.z, acc); acc = fmaf(qv.z*xv.z, cw.z, acc);
    acc = fmaf(qv.w, aw.w, acc); acc = fmaf(xv.w, bw.w, acc); acc = fmaf(qv.w*xv.w, cw.w, acc);
  }
  h1[(size_t)bt*32 + c] = acc;
}

// ---------- batch-axis stats (Dice): one thread per (t, channel) ----------
__global__ void k_stat(const float* __restrict__ hbuf, int ncols,
                       float* __restrict__ mu, float* __restrict__ rstd)
{
  int i = blockIdx.x*blockDim.x + threadIdx.x;
  float s = 0.f, s2 = 0.f;
  for (int b = 0; b < B; ++b){
    float v = hbuf[(size_t)b*ncols + i];
    s += v; s2 = fmaf(v, v, s2);
  }
  float m = s * (1.0f/B);
  float var = fmaxf(s2*(1.0f/B) - m*m, 0.f);
  mu[i] = m;
  rstd[i] = rsqrtf(var + 1e-9f);
}

// ---------- Dice gate in-place on h1 ----------
__global__ void k_gate1(float* __restrict__ h1, const float* __restrict__ mu, const float* __restrict__ rstd,
                        const float* __restrict__ alpha)
{
  float al = alpha[0];
  size_t i4 = ((size_t)blockIdx.x*blockDim.x + threadIdx.x)*4;
  float4 v  = *(const float4*)(h1 + i4);
  int s = (int)(i4 & 8191);
  float4 m  = *(const float4*)(mu + s);
  float4 rs = *(const float4*)(rstd + s);
  float p0 = sgm((v.x-m.x)*rs.x), p1 = sgm((v.y-m.y)*rs.y);
  float p2 = sgm((v.z-m.z)*rs.z), p3 = sgm((v.w-m.w)*rs.w);
  v.x *= p0 + al*(1.f-p0); v.y *= p1 + al*(1.f-p1);
  v.z *= p2 + al*(1.f-p2); v.w *= p3 + al*(1.f-p3);
  *(float4*)(h1 + i4) = v;
}

// ---------- attention dense 2 (pre-activation) ----------
__global__ void k_h2(const float* __restrict__ h1, const float* __restrict__ W2T, const float* __restrict__ b2,
                     float* __restrict__ h2)
{
  int d = threadIdx.x & 15;
  int p = threadIdx.x >> 4;
  int bt = blockIdx.x*16 + p;
  const float4* hp = (const float4*)(h1 + (size_t)bt*32);
  const float4* w4 = (const float4*)(W2T + d*32);
  float acc = b2[d];
  #pragma unroll
  for (int c4 = 0; c4 < 8; ++c4){
    float4 hv = hp[c4], wv = w4[c4];
    acc = fmaf(hv.x, wv.x, acc); acc = fmaf(hv.y, wv.y, acc);
    acc = fmaf(hv.z, wv.z, acc); acc = fmaf(hv.w, wv.w, acc);
  }
  h2[(size_t)bt*16 + d] = acc;
}

// ---------- Dice gate on h2 + dense 3 -> att score ----------
__global__ void k_att3(const float* __restrict__ h2, const float* __restrict__ mu2, const float* __restrict__ rstd2,
                       const float* __restrict__ alpha2, const float* __restrict__ W3, const float* __restrict__ b3,
                       float* __restrict__ att)
{
  float al = alpha2[0];
  int bt = blockIdx.x*blockDim.x + threadIdx.x;
  int t = bt & (T-1);
  const float* hp = h2 + (size_t)bt*16;
  const float* m  = mu2 + t*16;
  const float* rs = rstd2 + t*16;
  float acc = b3[0];
  #pragma unroll
  for (int d = 0; d < 16; ++d){
    float v = hp[d];
    float p = sgm((v - m[d])*rs[d]);
    acc = fmaf(v*(p + al*(1.f-p)), W3[d], acc);
  }
  att[bt] = acc;
}

// ---------- input-side GEMM: xi[t][b][384] = x @ [w_ir|w_iz|w_ih] + folded biases ----------
template<typename XT>
__global__ void k_xi(const float* __restrict__ x, const float* __restrict__ wcat, const float* __restrict__ bcat,
                     XT* __restrict__ xi)
{
  __shared__ float xs[64][132];   // [local bt row][k], padded
  __shared__ float wsh[128][68];  // [k][local j], padded
  int tid = threadIdx.x;
  int btBase = blockIdx.x*64;
  int jBase  = blockIdx.y*64;
  for (int i = tid; i < 64*32; i += 256){
    int r = i >> 5, e4 = i & 31;
    float4 v = *(const float4*)(x + (size_t)(btBase + r)*E + e4*4);
    *(float4*)&xs[r][e4*4] = v;
  }
  for (int i = tid; i < 128*16; i += 256){
    int k = i >> 4, j4 = i & 15;
    float4 v = *(const float4*)(wcat + (size_t)k*384 + jBase + j4*4);
    *(float4*)&wsh[k][j4*4] = v;
  }
  __syncthreads();
  int tx = tid & 15, ty = tid >> 4;
  float acc[4][4];
  #pragma unroll
  for (int i = 0; i < 4; ++i)
    #pragma unroll
    for (int jj = 0; jj < 4; ++jj) acc[i][jj] = bcat[jBase + tx*4 + jj];

  #pragma unroll 4
  for (int kt = 0; kt < 128; kt += 4){
    float4 av[4], bv[4];
    #pragma unroll
    for (int i = 0; i < 4; ++i) av[i] = *(const float4*)&xs[ty*4+i][kt];
    #pragma unroll
    for (int qq = 0; qq < 4; ++qq) bv[qq] = *(const float4*)&wsh[kt+qq][tx*4];
    #pragma unroll
    for (int i = 0; i < 4; ++i){
      float a0 = av[i].x, a1 = av[i].y, a2 = av[i].z, a3 = av[i].w;
      acc[i][0]=fmaf(a0,bv[0].x,acc[i][0]); acc[i][0]=fmaf(a1,bv[1].x,acc[i][0]);
      acc[i][0]=fmaf(a2,bv[2].x,acc[i][0]); acc[i][0]=fmaf(a3,bv[3].x,acc[i][0]);
      acc[i][1]=fmaf(a0,bv[0].y,acc[i][1]); acc[i][1]=fmaf(a1,bv[1].y,acc[i][1]);
      acc[i][1]=fmaf(a2,bv[2].y,acc[i][1]); acc[i][1]=fmaf(a3,bv[3].y,acc[i][1]);
      acc[i][2]=fmaf(a0,bv[0].z,acc[i][2]); acc[i][2]=fmaf(a1,bv[1].z,acc[i][2]);
      acc[i][2]=fmaf(a2,bv[2].z,acc[i][2]); acc[i][2]=fmaf(a3,bv[3].z,acc[i][2]);
      acc[i][3]=fmaf(a0,bv[0].w,acc[i][3]); acc[i][3]=fmaf(a1,bv[1].w,acc[i][3]);
      acc[i][3]=fmaf(a2,bv[2].w,acc[i][3]); acc[i][3]=fmaf(a3,bv[3].w,acc[i][3]);
    }
  }
  #pragma unroll
  for (int i = 0; i < 4; ++i){
    int bt = btBase + ty*4 + i;
    int b = bt >> 8, t = bt & (T-1);
    XT* op = xi + ((size_t)t*B + b)*384 + jBase + tx*4;
    if constexpr (sizeof(XT) == 4){
      *(float4*)op = make_float4(acc[i][0], acc[i][1], acc[i][2], acc[i][3]);
    } else {
      op[0] = __float2bfloat16(acc[i][0]); op[1] = __float2bfloat16(acc[i][1]);
      op[2] = __float2bfloat16(acc[i][2]); op[3] = __float2bfloat16(acc[i][3]);
    }
  }
}

// ---------- AUGRU recurrence: 4 batch rows/block, independent per block ----------
template<typename XT>
__global__ void __launch_bounds__(256, 1) k_rec(
    const float* __restrict__ whr, const float* __restrict__ whz, const float* __restrict__ whh,
    const float* __restrict__ bhh, const XT* __restrict__ xi, const float* __restrict__ att,
    const int* __restrict__ mask, float* __restrict__ out)
{
  __shared__ float wr_s[128*128];
  __shared__ float wz_s[128*128];
  __shared__ float hs[4*128];
  int tid = threadIdx.x;
  int j  = tid & 127;
  int rp = tid >> 7;            // row-pair id: 0 or 1
  int rA = rp*2;                // local rows rA, rA+1
  int gA = blockIdx.x*4 + rA;   // global batch rows gA, gA+1

  for (int i = tid; i < 4096; i += 256){
    ((float4*)wr_s)[i] = ((const float4*)whr)[i];
    ((float4*)wz_s)[i] = ((const float4*)whz)[i];
  }
  hs[tid] = 0.f; hs[256 + tid] = 0.f;

  float rh[128];                 // w_hh column j in registers
  #pragma unroll
  for (int k = 0; k < 128; ++k) rh[k] = whh[k*128 + j];
  float bhhj = bhh[j];
  float hc0 = 0.f, hc1 = 0.f;
  __syncthreads();

  for (int t = 0; t < T; ++t){
    // issue step-t streams early; consumed after the matvec
    const XT* xp = xi + ((size_t)t*B + gA)*384;
    float xr0 = cvt(xp[j]),       xr1 = cvt(xp[384 + j]);
    float xz0 = cvt(xp[128 + j]), xz1 = cvt(xp[384 + 128 + j]);
    float xh0 = cvt(xp[256 + j]), xh1 = cvt(xp[384 + 256 + j]);
    float aA = att[(size_t)gA*T + t];
    float aB = att[(size_t)(gA+1)*T + t];
    int mA = mask[(size_t)gA*T + t];
    int mB = mask[(size_t)(gA+1)*T + t];

    float ar0 = 0.f, ar1 = 0.f, az0 = 0.f, az1 = 0.f, ah0 = 0.f, ah1 = 0.f;
    const float* hsA = hs + rA*128;
    const float* hsB = hsA + 128;
    #pragma unroll
    for (int kt = 0; kt < 128; kt += 4){
      float4 hA = *(const float4*)(hsA + kt);
      float4 hB = *(const float4*)(hsB + kt);
      float w0 = wr_s[(kt+0)*128 + j], w1 = wr_s[(kt+1)*128 + j],
            w2 = wr_s[(kt+2)*128 + j], w3 = wr_s[(kt+3)*128 + j];
      ar0 = fmaf(hA.x,w0,ar0); ar0 = fmaf(hA.y,w1,ar0); ar0 = fmaf(hA.z,w2,ar0); ar0 = fmaf(hA.w,w3,ar0);
      ar1 = fmaf(hB.x,w0,ar1); ar1 = fmaf(hB.y,w1,ar1); ar1 = fmaf(hB.z,w2,ar1); ar1 = fmaf(hB.w,w3,ar1);
      float z0 = wz_s[(kt+0)*128 + j], z1 = wz_s[(kt+1)*128 + j],
            z2 = wz_s[(kt+2)*128 + j], z3 = wz_s[(kt+3)*128 + j];
      az0 = fmaf(hA.x,z0,az0); az0 = fmaf(hA.y,z1,az0); az0 = fmaf(hA.z,z2,az0); az0 = fmaf(hA.w,z3,az0);
      az1 = fmaf(hB.x,z0,az1); az1 = fmaf(hB.y,z1,az1); az1 = fmaf(hB.z,z2,az1); az1 = fmaf(hB.w,z3,az1);
      ah0 = fmaf(hA.x,rh[kt+0],ah0); ah0 = fmaf(hA.y,rh[kt+1],ah0);
      ah0 = fmaf(hA.z,rh[kt+2],ah0); ah0 = fmaf(hA.w,rh[kt+3],ah0);
      ah1 = fmaf(hB.x,rh[kt+0],ah1); ah1 = fmaf(hB.y,rh[kt+1],ah1);
      ah1 = fmaf(hB.z,rh[kt+2],ah1); ah1 = fmaf(hB.w,rh[kt+3],ah1);
    }
    float rr0 = sgm(ar0 + xr0), rr1 = sgm(ar1 + xr1);
    float zz0 = sgm(az0 + xz0)*aA, zz1 = sgm(az1 + xz1)*aB;
    float hh0 = tanhf(fmaf(rr0, ah0 + bhhj, xh0));
    float hh1 = tanhf(fmaf(rr1, ah1 + bhhj, xh1));
    float hn0 = (1.f - zz0)*hc0 + zz0*hh0;
    float hn1 = (1.f - zz1)*hc1 + zz1*hh1;
    hn0 = (mA > 0) ? hn0 : hc0;
    hn1 = (mB > 0) ? hn1 : hc1;
    __syncthreads();
    hs[rA*128 + j]     = hn0;
    hs[(rA+1)*128 + j] = hn1;
    hc0 = hn0; hc1 = hn1;
    __syncthreads();
  }
  out[(size_t)gA*E + j]     = hc0;
  out[(size_t)(gA+1)*E + j] = hc1;
}

} // namespace

extern "C" void kernel_launch(void* const* d_in, const int* in_sizes, int n_in,
                              void* d_out, int out_size, void* d_ws, size_t ws_size,
                              hipStream_t stream)
{
  (void)in_sizes; (void)n_in; (void)out_size;
  const float* q   = (const float*)d_in[0];
  const float* x   = (const float*)d_in[1];
  const int*   msk = (const int*)d_in[2];
  const float* W1  = (const float*)d_in[3];
  const float* b1  = (const float*)d_in[4];
  const float* al1 = (const float*)d_in[5];
  const float* W2  = (const float*)d_in[6];
  const float* b2  = (const float*)d_in[7];
  const float* al2 = (const float*)d_in[8];
  const float* W3  = (const float*)d_in[9];
  const float* b3  = (const float*)d_in[10];
  const float* w_ir= (const float*)d_in[11];
  const float* w_hr= (const float*)d_in[12];
  const float* b_ir= (const float*)d_in[13];
  const float* b_hr= (const float*)d_in[14];
  const float* w_iz= (const float*)d_in[15];
  const float* w_hz= (const float*)d_in[16];
  const float* b_iz= (const float*)d_in[17];
  const float* b_hz= (const float*)d_in[18];
  const float* w_ih= (const float*)d_in[19];
  const float* w_hh= (const float*)d_in[20];
  const float* b_ih= (const float*)d_in[21];
  const float* b_hh= (const float*)d_in[22];
  float* out = (float*)d_out;

  // ws layout (float offsets)
  float* ws   = (float*)d_ws;
  float* wqT  = ws + 0;        // 4096
  float* wxT  = ws + 4096;     // 4096
  float* wqxT = ws + 8192;     // 4096
  float* W2T  = ws + 12288;    // 512
  float* wcat = ws + 12800;    // 49152
  float* bcat = ws + 61952;    // 384
  float* mu1  = ws + 62336;    // 8192
  float* rs1  = ws + 70528;    // 8192
  float* mu2  = ws + 78720;    // 4096
  float* rs2  = ws + 82816;    // 4096
  float* att  = ws + 87040;    // 262144
  float* h1   = ws + 349184;   // 8388608
  float* h2   = ws + 8737792;  // 4194304
  const size_t base_f = 12932096;
  void* xi = (void*)(ws + base_f);

  const size_t need_f32  = (base_f + (size_t)BT*384)*sizeof(float);
  const size_t need_bf16 = base_f*sizeof(float) + (size_t)BT*384*sizeof(__hip_bfloat16);
  if (ws_size < need_bf16) return;  // cannot run without scratch; avoid OOB writes

  k_prep<<<64, 256, 0, stream>>>(W1, W2, w_ir, w_iz, w_ih, b_ir, b_hr, b_iz, b_hz, b_ih,
                                 wqT, wxT, wqxT, W2T, wcat, bcat);
  k_h1<<<BT/8, 256, 0, stream>>>(q, x, wqT, wxT, wqxT, b1, h1);
  k_stat<<<32, 256, 0, stream>>>(h1, T*32, mu1, rs1);
  k_gate1<<<BT*32/1024, 256, 0, stream>>>(h1, mu1, rs1, al1);
  k_h2<<<BT/16, 256, 0, stream>>>(h1, W2T, b2, h2);
  k_stat<<<16, 256, 0, stream>>>(h2, T*16, mu2, rs2);
  k_att3<<<BT/256, 256, 0, stream>>>(h2, mu2, rs2, al2, W3, b3, att);

  if (ws_size >= need_f32){
    k_xi<float><<<dim3(BT/64, 6), 256, 0, stream>>>(x, wcat, bcat, (float*)xi);
    k_rec<float><<<B/4, 256, 0, stream>>>(w_hr, w_hz, w_hh, b_hh, (const float*)xi, att, msk, out);
  } else {
    k_xi<__hip_bfloat16><<<dim3(BT/64, 6), 256, 0, stream>>>(x, wcat, bcat, (__hip_bfloat16*)xi);
    k_rec<__hip_bfloat16><<<B/4, 256, 0, stream>>>(w_hr, w_hz, w_hh, b_hh, (const __hip_bfloat16*)xi, att, msk, out);
  }
}